// Round 15
// baseline (124.515 us; speedup 1.0000x reference)
//
#include <hip/hip_runtime.h>
#include <math.h>

#define BB   4
#define DIM  64
#define RES  128
#define WIN  16
#define WS   32

typedef __attribute__((ext_vector_type(8))) short bf16x8;
typedef __attribute__((ext_vector_type(4))) float f32x4;

static __device__ __forceinline__ unsigned short bf16_rne(float f) {
  unsigned int u = __float_as_uint(f);
  u += 0x7FFFu + ((u >> 16) & 1u);
  return (unsigned short)(u >> 16);
}
static __device__ __forceinline__ float bf16_f(unsigned short h) {
  return __uint_as_float(((unsigned int)h) << 16);
}

// ---------------------------------------------------------------------------
// Kernel 1a: per-(b,w,stripe) partial aggregates of x over the 32x32 window.
// 256 blocks (full chip) x 512 thr; each stripe = 8 rows. Writes
// part_g[blk][5][64] = {T, R0, RL, C0, CL} partials.
// ---------------------------------------------------------------------------
__global__ __launch_bounds__(512) void k_pooled_a(
    const float* __restrict__ x, float* __restrict__ part_g)
{
  const int blk = blockIdx.x;               // b*64 + w*4 + st
  const int b = blk >> 6, w = (blk >> 2) & 15, st = blk & 3;
  const int wy = w >> 2, wx = w & 3;
  const int c = threadIdx.x & 63, rg = threadIdx.x >> 6;  // 8 rows/stripe
  const int i = st * 8 + rg;                // window row 0..31
  const int gr = wy * WS + i;               // global row
  const float* xr = x + ((size_t)b * RES * RES + (size_t)gr * RES + wx * WS) * DIM + c;

  float rs = 0.f, v0 = 0.f, vL = 0.f;
#pragma unroll 8
  for (int j = 0; j < 32; ++j) {
    float v = xr[(size_t)j * DIM];
    rs += v;
    if (j == 0)  v0 = v;
    if (j == 31) vL = v;
  }

  __shared__ float part[8][5][64];
  part[rg][0][c] = rs;
  part[rg][1][c] = (i == 0)  ? rs : 0.f;   // window row 0 sum
  part[rg][2][c] = (i == 31) ? rs : 0.f;   // window row 31 sum
  part[rg][3][c] = v0;                     // col-0 contribution
  part[rg][4][c] = vL;                     // col-31 contribution
  __syncthreads();

  if (threadIdx.x < 320) {
    const int a = threadIdx.x >> 6, cc = threadIdx.x & 63;
    float s = 0.f;
#pragma unroll
    for (int r = 0; r < 8; ++r) s += part[r][a][cc];
    part_g[(((size_t)blk) * 5 + a) * 64 + cc] = s;
  }
}

// ---------------------------------------------------------------------------
// Kernel 2: per-(b,o) block. Prologue reduces stripe partials -> pooled
// (shifted-window-sum algebra + corners), then tiny MLP, then
// Keff[k=tap*64+c] transposed & split bf16 hi/lo: keffT_{hi,lo}[b][o][576].
// ---------------------------------------------------------------------------
__global__ __launch_bounds__(576) void k_keff(
    const float* __restrict__ x, const float* __restrict__ part_g,
    const float* __restrict__ conv1_w,
    const float* __restrict__ dc_w, const float* __restrict__ dc_b,
    const float* __restrict__ l1_w, const float* __restrict__ l1_b,
    const float* __restrict__ l2_w, const float* __restrict__ l2_b,
    const float* __restrict__ gk_w, const float* __restrict__ gk_b,
    const float* __restrict__ fus_w,
    unsigned short* __restrict__ kT_hi, unsigned short* __restrict__ kT_lo)
{
  const int b = blockIdx.x >> 6, o = blockIdx.x & 63;
  const int tid = threadIdx.x;
  __shared__ float agg[5][16][64];        // [aggregate][w][c]
  __shared__ float pooled_s[16][64];
  __shared__ float w1s[16], hs[64], w2s[16], gkws[16];

  // ---- reduce 4 stripes ----
  for (int idx = tid; idx < 5 * 16 * 64; idx += 576) {
    const int a = idx >> 10, rem = idx & 1023, w = rem >> 6, cc = rem & 63;
    float s = 0.f;
#pragma unroll
    for (int st = 0; st < 4; ++st)
      s += part_g[((((size_t)b * 16 + w) * 4 + st) * 5 + a) * 64 + cc];
    agg[a][w][cc] = s;
  }
  __syncthreads();

  // ---- pooled via shifted-window algebra ----
  for (int idx = tid; idx < 16 * 64; idx += 576) {
    const int w = idx >> 6, cc = idx & 63;
    const int wy = w >> 2, wx = w & 3;
    const float* xb = x + (size_t)b * RES * RES * DIM + cc;
    const size_t b00 = (size_t)(wy * WS * RES + wx * WS) * DIM;
    const float x00 = xb[b00];
    const float x0L = xb[b00 + 31 * DIM];
    const float xL0 = xb[b00 + (size_t)31 * RES * DIM];
    const float xLL = xb[b00 + (size_t)31 * RES * DIM + 31 * DIM];
    const float t  = agg[0][w][cc], r0 = agg[1][w][cc], rl = agg[2][w][cc],
                c0 = agg[3][w][cc], cl = agg[4][w][cc];
    const float* bw = conv1_w + (size_t)(w * DIM + cc) * 9;
    float p = 0.f;
#pragma unroll
    for (int ky = 0; ky < 3; ++ky) {
#pragma unroll
      for (int kx = 0; kx < 3; ++kx) {
        const int dy = ky - 1, dx = kx - 1;
        float S = t;
        if (dy == 1)  S -= r0;
        if (dy == -1) S -= rl;
        if (dx == 1)  S -= c0;
        if (dx == -1) S -= cl;
        if (dy == 1 && dx == 1)   S += x00;
        if (dy == 1 && dx == -1)  S += x0L;
        if (dy == -1 && dx == 1)  S += xL0;
        if (dy == -1 && dx == -1) S += xLL;
        p += bw[ky * 3 + kx] * S;
      }
    }
    pooled_s[w][cc] = p * (1.0f / 1024.0f);
  }
  __syncthreads();

  // ---- tiny MLP ----
  if (tid < 16) {
    float s = dc_b[tid];
    const float* dw = dc_w + tid * 64;
    for (int cc = 0; cc < 64; ++cc) s += pooled_s[tid][cc] * dw[cc];
    w1s[tid] = s;
    gkws[tid] = gk_w[tid];
  }
  __syncthreads();
  if (tid < 64) {
    float s = l1_b[tid];
    for (int g = 0; g < 16; ++g) s += w1s[g] * l1_w[tid * 16 + g];
    hs[tid] = 0.5f * s * (1.0f + erff(s * 0.70710678118654752f));  // exact GELU
  }
  __syncthreads();
  if (tid < 16) {
    float s = l2_b[tid];
    for (int j = 0; j < 64; ++j) s += hs[j] * l2_w[tid * 64 + j];
    w2s[tid] = 1.0f / (1.0f + expf(-s));
  }
  __syncthreads();

  // tid IS the GEMM k-index: k = tap*64 + c
  const int tap = tid >> 6, c = tid & 63;
  const float f1 = fus_w[o * 1088 + 1024 + c];
  float acc = gk_b[0] * f1;
#pragma unroll
  for (int g = 0; g < 16; ++g) {
    acc += w2s[g] * conv1_w[(size_t)(g * 64 + c) * 9 + tap] *
           (fus_w[o * 1088 + g * 64 + c] + gkws[g] * f1);
  }
  const unsigned short h = bf16_rne(acc);
  const unsigned short lo = bf16_rne(acc - bf16_f(h));
  const size_t kidx = (size_t)(b * 64 + o) * 576 + tid;
  kT_hi[kidx] = h;
  kT_lo[kidx] = lo;
}

// ---------------------------------------------------------------------------
// Kernel 3: implicit-GEMM conv, MFMA 16x16x32 bf16 split hi/lo. UNCHANGED
// from r12 (o-split waves, 32.6 KB LDS, 4 blocks/CU).
// ---------------------------------------------------------------------------
__global__ __launch_bounds__(256, 4) void k_conv(
    const float* __restrict__ x,
    const unsigned short* __restrict__ kT_hi,
    const unsigned short* __restrict__ kT_lo,
    const float* __restrict__ fus_b, float* __restrict__ out)
{
  const int bid = blockIdx.x;
  const int b = bid >> 8;
  const int rem = bid & 255;
  const int row = rem >> 1;
  const int colbase = (rem & 1) * 64;
  const int tid = threadIdx.x;
  const int l = tid & 63, wv = tid >> 6;     // lane, wave (o-slice)
  const int l16 = l & 15, lq = l >> 4;

  __shared__ unsigned short xs_hi[3][68][40];  // [halo row][col+1 (0..65)][32ch pad40]
  __shared__ unsigned short xs_lo[3][68][40];

  f32x4 acc[4];
#pragma unroll
  for (int mf = 0; mf < 4; ++mf) acc[mf] = (f32x4){0.f, 0.f, 0.f, 0.f};

  const float* xb = x + (size_t)b * RES * RES * DIM;
  const unsigned short* khB = kT_hi + (size_t)b * 64 * 576;
  const unsigned short* klB = kT_lo + (size_t)b * 64 * 576;

  for (int ch = 0; ch < 2; ++ch) {
    const int c0 = ch * 32;
    // ---- stage x halo rows: 3 rows x cols (colbase-1 .. colbase+64) x 32 ch ----
    for (int i = tid; i < 3 * 66 * 8; i += 256) {
      const int rr  = i / (66 * 8);
      const int rem2 = i - rr * (66 * 8);
      const int cs  = rem2 >> 3;          // 0..65
      const int c4  = rem2 & 7;           // float4 group within 32 ch
      const int col = colbase + cs - 1;
      const int grow = row - 1 + rr;
      float4 v = make_float4(0.f, 0.f, 0.f, 0.f);
      if (grow >= 0 && grow < RES && col >= 0 && col < RES)
        v = *(const float4*)(xb + (size_t)(grow * RES + col) * DIM + c0 + c4 * 4);
      const unsigned short h0 = bf16_rne(v.x), h1 = bf16_rne(v.y),
                           h2 = bf16_rne(v.z), h3 = bf16_rne(v.w);
      const unsigned short q0 = bf16_rne(v.x - bf16_f(h0)),
                           q1 = bf16_rne(v.y - bf16_f(h1)),
                           q2 = bf16_rne(v.z - bf16_f(h2)),
                           q3 = bf16_rne(v.w - bf16_f(h3));
      *(ushort4*)&xs_hi[rr][cs][c4 * 4] = make_ushort4(h0, h1, h2, h3);
      *(ushort4*)&xs_lo[rr][cs][c4 * 4] = make_ushort4(q0, q1, q2, q3);
    }
    __syncthreads();

#pragma unroll
    for (int tap = 0; tap < 9; ++tap) {
      const int dy = tap / 3 - 1, dx = tap % 3 - 1;
      const int kb = tap * 64 + c0 + lq * 8;
      // B: this wave's o-slice only (o = wv*16 + l16)
      const size_t ko = (size_t)(wv * 16 + l16) * 576 + kb;
      const bf16x8 Bh = *(const bf16x8*)(khB + ko);
      const bf16x8 Bl = *(const bf16x8*)(klB + ko);
#pragma unroll
      for (int mf = 0; mf < 4; ++mf) {
        const int cs = 1 + mf * 16 + l16 + dx;   // pixel col in LDS
        const bf16x8 Ah = *(const bf16x8*)&xs_hi[dy + 1][cs][lq * 8];
        const bf16x8 Al = *(const bf16x8*)&xs_lo[dy + 1][cs][lq * 8];
        acc[mf] = __builtin_amdgcn_mfma_f32_16x16x32_bf16(Ah, Bh, acc[mf], 0, 0, 0);
        acc[mf] = __builtin_amdgcn_mfma_f32_16x16x32_bf16(Ah, Bl, acc[mf], 0, 0, 0);
        acc[mf] = __builtin_amdgcn_mfma_f32_16x16x32_bf16(Al, Bh, acc[mf], 0, 0, 0);
      }
    }
    __syncthreads();
  }

  // ---- store: D layout col(o)=lane&15, row(px)=(lane>>4)*4+reg [m89] ----
  const float fb = fus_b[wv * 16 + l16];
  const size_t pbase = (size_t)b * RES * RES + (size_t)row * RES + colbase;
#pragma unroll
  for (int mf = 0; mf < 4; ++mf) {
    const int pc = mf * 16 + lq * 4;
#pragma unroll
    for (int r4 = 0; r4 < 4; ++r4) {
      out[(pbase + pc + r4) * DIM + wv * 16 + l16] = acc[mf][r4] + fb;
    }
  }
}

// ---------------------------------------------------------------------------
extern "C" void kernel_launch(void* const* d_in, const int* in_sizes, int n_in,
                              void* d_out, int out_size, void* d_ws, size_t ws_size,
                              hipStream_t stream) {
  const float* x       = (const float*)d_in[0];
  const float* conv1_w = (const float*)d_in[1];
  const float* dc_w    = (const float*)d_in[2];
  const float* dc_b    = (const float*)d_in[3];
  const float* l1_w    = (const float*)d_in[4];
  const float* l1_b    = (const float*)d_in[5];
  const float* l2_w    = (const float*)d_in[6];
  const float* l2_b    = (const float*)d_in[7];
  const float* gk_w    = (const float*)d_in[8];
  const float* gk_b    = (const float*)d_in[9];
  const float* fus_w   = (const float*)d_in[10];
  const float* fus_b   = (const float*)d_in[11];
  float* out = (float*)d_out;

  // workspace: part_g (320 KB) | keffT_hi (288 KB) | keffT_lo (288 KB)
  float* part_g = (float*)d_ws;
  unsigned short* kT_hi = (unsigned short*)((char*)d_ws + 327680);
  unsigned short* kT_lo = kT_hi + (size_t)BB * 64 * 576;

  hipLaunchKernelGGL(k_pooled_a, dim3(BB * WIN * 4), dim3(512), 0, stream,
                     x, part_g);
  hipLaunchKernelGGL(k_keff, dim3(BB * 64), dim3(576), 0, stream,
                     x, part_g, conv1_w, dc_w, dc_b, l1_w, l1_b, l2_w, l2_b,
                     gk_w, gk_b, fus_w, kT_hi, kT_lo);
  hipLaunchKernelGGL(k_conv, dim3(BB * RES * 2), dim3(256), 0, stream,
                     x, kT_hi, kT_lo, fus_b, out);
}